// Round 15
// baseline (122.474 us; speedup 1.0000x reference)
//
#include <hip/hip_runtime.h>

typedef __attribute__((ext_vector_type(4))) float f32x4;
typedef __attribute__((ext_vector_type(8))) short s16x8;

#define MFMA16(a, b, c) __builtin_amdgcn_mfma_f32_16x16x32_bf16((a), (b), (c), 0, 0, 0)

__device__ __forceinline__ unsigned short f2bf(float f) {
    union { float f; unsigned u; } v; v.f = f;
    unsigned u = v.u + 0x7FFFu + ((v.u >> 16) & 1u);
    return (unsigned short)(u >> 16);
}

__device__ __forceinline__ float bf2f(unsigned short u) {
    union { unsigned u; float f; } v; v.u = ((unsigned)u) << 16;
    return v.f;
}

__device__ __forceinline__ unsigned cvtpk(float lo, float hi) {
    unsigned r;
    asm("v_cvt_pk_bf16_f32 %0, %1, %2" : "=v"(r) : "v"(lo), "v"(hi));
    return r;
}

__device__ __forceinline__ float exp2f_fast(float x) {
    float r;
    asm("v_exp_f32 %0, %1" : "=v"(r) : "v"(x));
    return r;
}

__device__ __forceinline__ void gll16(const unsigned short* g, unsigned short* l) {
    __builtin_amdgcn_global_load_lds((const __attribute__((address_space(1))) void*)g,
                                     (__attribute__((address_space(3))) void*)l, 16, 0, 0);
}

// ---- kernel 1+2 fused: weight convert (blocks >= 512) / group-norm (blocks < 512) ----
// Single-HBM-pass GN: pass 1 accumulates fp32 stats AND caches x as bf16 in LDS;
// pass 2 normalizes from the LDS cache (no second global read of x).
__global__ __launch_bounds__(256) void k_gnw(const float* __restrict__ x,
                                             const float* __restrict__ gnw,
                                             const float* __restrict__ gnb,
                                             const float* __restrict__ qkv_w,
                                             const float* __restrict__ proj_w,
                                             unsigned short* __restrict__ h_t,
                                             unsigned short* __restrict__ wout) {
    __shared__ float rs[4], rss[4], mv[2];
    __shared__ unsigned short xl[16][1024];   // bf16 x cache (32KB)
    __shared__ unsigned short ldt[1024][18];  // padded transpose buffer (36KB)
    int blk = blockIdx.x;
    int t = threadIdx.x;
    if (blk >= 512) {
        int i = (blk - 512) * 256 + t;
        const int NQ = 3 * 512 * 512;
        float v = (i < NQ) ? qkv_w[i] : proj_w[i - NQ];
        wout[i] = f2bf(v);
        return;
    }
    int bg = blk;
    int b = bg >> 5, g = bg & 31;
    const float4* p = (const float4*)(x + (size_t)bg * 16384);
    float s = 0.f, ss = 0.f;
    for (int i = t; i < 4096; i += 256) {
        float4 v = p[i];
        s += v.x + v.y + v.z + v.w;
        ss += v.x * v.x + v.y * v.y + v.z * v.z + v.w * v.w;
        int c = i >> 8, n = (i << 2) & 1023;
        xl[c][n + 0] = f2bf(v.x);
        xl[c][n + 1] = f2bf(v.y);
        xl[c][n + 2] = f2bf(v.z);
        xl[c][n + 3] = f2bf(v.w);
    }
    for (int w = 1; w < 64; w <<= 1) { s += __shfl_xor(s, w); ss += __shfl_xor(ss, w); }
    int wid = t >> 6;
    if ((t & 63) == 0) { rs[wid] = s; rss[wid] = ss; }
    __syncthreads();
    if (t == 0) {
        float S = rs[0] + rs[1] + rs[2] + rs[3];
        float SS = rss[0] + rss[1] + rss[2] + rss[3];
        float mean = S * (1.f / 16384.f);
        float var = SS * (1.f / 16384.f) - mean * mean;
        mv[0] = mean; mv[1] = rsqrtf(var + 1e-5f);
    }
    __syncthreads();
    int c = t >> 4, f4 = t & 15;
    float mean = mv[0], rstd = mv[1];
    float sc = gnw[g * 16 + c] * rstd;
    float sh = gnb[g * 16 + c] - mean * sc;
#pragma unroll
    for (int i = 0; i < 16; ++i) {
        int n = i * 64 + f4 * 4;
        ushort4 xv = *(const ushort4*)&xl[c][n];
        ldt[n + 0][c] = f2bf(bf2f(xv.x) * sc + sh);
        ldt[n + 1][c] = f2bf(bf2f(xv.y) * sc + sh);
        ldt[n + 2][c] = f2bf(bf2f(xv.z) * sc + sh);
        ldt[n + 3][c] = f2bf(bf2f(xv.w) * sc + sh);
    }
    __syncthreads();
    int half = t & 1;
#pragma unroll
    for (int i = 0; i < 8; ++i) {
        int row = i * 128 + (t >> 1);
        *(uint4*)(h_t + ((size_t)(b * 1024 + row)) * 512 + g * 16 + half * 8) =
            *(const uint4*)(&ldt[row][half * 8]);
    }
}

// ---- merged QKV BT-GEMM, 128x128 tile, 8 waves (wave-tile 64x32), K=512 ----
// mt 0..7: Q/K tiles, unswapped MFMA, uint2 bf16 stores
// mt 8..11: V tiles, swapped MFMA (D rows = pixels), permuted-m uint2 stores
// Block-uniform branch, two separate loop bodies (no per-iteration branching).
__global__ __launch_bounds__(512, 6) void k_gemmqkv(const unsigned short* __restrict__ A,
                                                    const unsigned short* __restrict__ Bt,
                                                    const float* __restrict__ bias,
                                                    unsigned short* __restrict__ Qo,
                                                    unsigned short* __restrict__ Ko,
                                                    unsigned short* __restrict__ Vo) {
    const int Kd = 512;
    int id = blockIdx.x;
    int xcd = id & 7, j = id >> 3;
    int nt = xcd + 8 * (j & 15);   // B-tile: 16 per XCD, L2-resident
    int mt = j >> 4;               // 0..11
    int t = threadIdx.x, wid = t >> 6, lane = t & 63;
    int lm = lane & 15, q4 = lane >> 4;
    int wm = wid >> 2, wn = wid & 3;  // 2 (m) x 4 (n) waves; wave-tile 64x32
    __shared__ unsigned short ldsA[2][4096];
    __shared__ unsigned short ldsB[2][4096];
    int m0 = mt * 128, n0 = nt * 128;

    int r = t >> 2;
    int cc = (t & 3) ^ (r & 3);  // chunk-XOR swizzle folded into global src
    const unsigned short* gA = A + (size_t)(m0 + r) * Kd + cc * 8;
    const unsigned short* gB = Bt + (size_t)(n0 + r) * Kd + cc * 8;
    unsigned short* dA[2] = { &ldsA[0][wid * 512], &ldsA[1][wid * 512] };
    unsigned short* dB[2] = { &ldsB[0][wid * 512], &ldsB[1][wid * 512] };

    f32x4 z = {0.f, 0.f, 0.f, 0.f};
    f32x4 acc[4][2];
#pragma unroll
    for (int fi = 0; fi < 4; ++fi)
#pragma unroll
        for (int fj = 0; fj < 2; ++fj) acc[fi][fj] = z;

    gll16(gA, dA[0]); gll16(gB, dB[0]);
    gA += 32; gB += 32;

    const int NK = 16;
    int b = nt >> 3;
    if (mt < 8) {
        // ---------------- unswapped loop (Q/K) ----------------
        for (int ks = 0; ks < NK; ++ks) {
            int cur = ks & 1;
            if (ks + 1 < NK) {
                gll16(gA, dA[cur ^ 1]); gll16(gB, dB[cur ^ 1]);
                gA += 32; gB += 32;
                asm volatile("s_waitcnt vmcnt(2)" ::: "memory");
            } else {
                asm volatile("s_waitcnt vmcnt(0)" ::: "memory");
            }
            __builtin_amdgcn_s_barrier();
            asm volatile("" ::: "memory");
            const unsigned short* lA = ldsA[cur];
            const unsigned short* lB = ldsB[cur];
            s16x8 af[4], bg[2];
#pragma unroll
            for (int fi = 0; fi < 4; ++fi) {
                int rA = wm * 64 + fi * 16 + lm;
                af[fi] = *(const s16x8*)&lA[(rA * 4 + (q4 ^ (lm & 3))) * 8];
            }
#pragma unroll
            for (int fj = 0; fj < 2; ++fj) {
                int rB = wn * 32 + fj * 16 + lm;
                bg[fj] = *(const s16x8*)&lB[(rB * 4 + (q4 ^ (lm & 3))) * 8];
            }
#pragma unroll
            for (int fi = 0; fi < 4; ++fi)
#pragma unroll
                for (int fj = 0; fj < 2; ++fj) acc[fi][fj] = MFMA16(af[fi], bg[fj], acc[fi][fj]);
            asm volatile("" ::: "memory");
            __builtin_amdgcn_s_barrier();
        }
        int part = mt >> 2;  // 0=Q (mt 0..3), 1=K (mt 4..7)
        int head = mt & 3;
        int bh = b * 4 + head;
        const float qscale = 0.08838834764831845f * 1.4426950408889634f;  // 1/sqrt(128)*log2e
#pragma unroll
        for (int fi = 0; fi < 4; ++fi) {
            int ddb = wm * 64 + fi * 16 + 4 * q4;
            float bv[4];
#pragma unroll
            for (int i = 0; i < 4; ++i) bv[i] = bias[mt * 128 + ddb + i];
#pragma unroll
            for (int fj = 0; fj < 2; ++fj) {
                int n = ((nt & 7) << 7) + wn * 32 + fj * 16 + lm;
                f32x4 v = acc[fi][fj];
                uint2 pr;
                if (part == 0) {
                    pr.x = cvtpk((v[0] + bv[0]) * qscale, (v[1] + bv[1]) * qscale);
                    pr.y = cvtpk((v[2] + bv[2]) * qscale, (v[3] + bv[3]) * qscale);
                    *(uint2*)(Qo + ((size_t)bh * 1024 + n) * 128 + ddb) = pr;
                } else {
                    pr.x = cvtpk(v[0] + bv[0], v[1] + bv[1]);
                    pr.y = cvtpk(v[2] + bv[2], v[3] + bv[3]);
                    *(uint2*)(Ko + ((size_t)bh * 1024 + n) * 128 + ddb) = pr;
                }
            }
        }
    } else {
        // ---------------- swapped loop (V) ----------------
        for (int ks = 0; ks < NK; ++ks) {
            int cur = ks & 1;
            if (ks + 1 < NK) {
                gll16(gA, dA[cur ^ 1]); gll16(gB, dB[cur ^ 1]);
                gA += 32; gB += 32;
                asm volatile("s_waitcnt vmcnt(2)" ::: "memory");
            } else {
                asm volatile("s_waitcnt vmcnt(0)" ::: "memory");
            }
            __builtin_amdgcn_s_barrier();
            asm volatile("" ::: "memory");
            const unsigned short* lA = ldsA[cur];
            const unsigned short* lB = ldsB[cur];
            s16x8 af[4], bg[2];
#pragma unroll
            for (int fi = 0; fi < 4; ++fi) {
                int rA = wm * 64 + fi * 16 + lm;
                af[fi] = *(const s16x8*)&lA[(rA * 4 + (q4 ^ (lm & 3))) * 8];
            }
#pragma unroll
            for (int fj = 0; fj < 2; ++fj) {
                int rB = wn * 32 + fj * 16 + lm;
                bg[fj] = *(const s16x8*)&lB[(rB * 4 + (q4 ^ (lm & 3))) * 8];
            }
#pragma unroll
            for (int fi = 0; fi < 4; ++fi)
#pragma unroll
                for (int fj = 0; fj < 2; ++fj) acc[fi][fj] = MFMA16(bg[fj], af[fi], acc[fi][fj]);
            asm volatile("" ::: "memory");
            __builtin_amdgcn_s_barrier();
        }
        // lane col lm = d, rows = pixel (4 consecutive) -> permuted uint2
        int bh = b * 4 + (mt & 3);
#pragma unroll
        for (int fi = 0; fi < 4; ++fi) {
            int d = wm * 64 + fi * 16 + lm;
            float bv = bias[mt * 128 + d];
#pragma unroll
            for (int fj = 0; fj < 2; ++fj) {
                int np = ((nt & 7) << 7) + wn * 32 + q4 * 8 + fj * 4;
                f32x4 v = acc[fi][fj];
                uint2 pr;
                pr.x = cvtpk(v[0] + bv, v[1] + bv);
                pr.y = cvtpk(v[2] + bv, v[3] + bv);
                *(uint2*)(Vo + ((size_t)bh * 128 + d) * 1024 + np) = pr;
            }
        }
    }
}

// ---------------- proj BT-GEMM (swapped), float4 xres/out epilogue ----------------
__global__ __launch_bounds__(512, 6) void k_gemmproj(const unsigned short* __restrict__ A,
                                                     const unsigned short* __restrict__ Bt,
                                                     const float* __restrict__ bias,
                                                     const float* __restrict__ xres,
                                                     float* __restrict__ out) {
    const int Kd = 512;
    int id = blockIdx.x;
    int xcd = id & 7, j = id >> 3;
    int nt = xcd + 8 * (j & 15);
    int mt = j >> 4;
    int t = threadIdx.x, wid = t >> 6, lane = t & 63;
    int lm = lane & 15, q4 = lane >> 4;
    int wm = wid >> 2, wn = wid & 3;
    __shared__ unsigned short ldsA[2][4096];
    __shared__ unsigned short ldsB[2][4096];
    int m0 = mt * 128, n0 = nt * 128;

    int r = t >> 2;
    int cc = (t & 3) ^ (r & 3);
    const unsigned short* gA = A + (size_t)(m0 + r) * Kd + cc * 8;
    const unsigned short* gB = Bt + (size_t)(n0 + r) * Kd + cc * 8;
    unsigned short* dA[2] = { &ldsA[0][wid * 512], &ldsA[1][wid * 512] };
    unsigned short* dB[2] = { &ldsB[0][wid * 512], &ldsB[1][wid * 512] };

    f32x4 z = {0.f, 0.f, 0.f, 0.f};
    f32x4 acc[4][2];
#pragma unroll
    for (int fi = 0; fi < 4; ++fi)
#pragma unroll
        for (int fj = 0; fj < 2; ++fj) acc[fi][fj] = z;

    gll16(gA, dA[0]); gll16(gB, dB[0]);
    gA += 32; gB += 32;

    const int NK = 16;
    for (int ks = 0; ks < NK; ++ks) {
        int cur = ks & 1;
        if (ks + 1 < NK) {
            gll16(gA, dA[cur ^ 1]); gll16(gB, dB[cur ^ 1]);
            gA += 32; gB += 32;
            asm volatile("s_waitcnt vmcnt(2)" ::: "memory");
        } else {
            asm volatile("s_waitcnt vmcnt(0)" ::: "memory");
        }
        __builtin_amdgcn_s_barrier();
        asm volatile("" ::: "memory");
        const unsigned short* lA = ldsA[cur];
        const unsigned short* lB = ldsB[cur];
        s16x8 af[4], bg[2];
#pragma unroll
        for (int fi = 0; fi < 4; ++fi) {
            int rA = wm * 64 + fi * 16 + lm;
            af[fi] = *(const s16x8*)&lA[(rA * 4 + (q4 ^ (lm & 3))) * 8];
        }
#pragma unroll
        for (int fj = 0; fj < 2; ++fj) {
            int rB = wn * 32 + fj * 16 + lm;
            bg[fj] = *(const s16x8*)&lB[(rB * 4 + (q4 ^ (lm & 3))) * 8];
        }
#pragma unroll
        for (int fi = 0; fi < 4; ++fi)
#pragma unroll
            for (int fj = 0; fj < 2; ++fj) acc[fi][fj] = MFMA16(bg[fj], af[fi], acc[fi][fj]);
        asm volatile("" ::: "memory");
        __builtin_amdgcn_s_barrier();
    }

    int b = nt >> 3;
#pragma unroll
    for (int fi = 0; fi < 4; ++fi) {
        int oc = m0 + wm * 64 + fi * 16 + lm;
        float bv = bias[oc];
#pragma unroll
        for (int fj = 0; fj < 2; ++fj) {
            int n = ((nt & 7) << 7) + wn * 32 + fj * 16 + 4 * q4;
            size_t idx = ((size_t)b * 512 + oc) * 1024 + n;
            float4 xr = *(const float4*)&xres[idx];
            f32x4 v = acc[fi][fj];
            float4 o;
            o.x = xr.x + bv + v[0];
            o.y = xr.y + bv + v[1];
            o.z = xr.z + bv + v[2];
            o.w = xr.w + bv + v[3];
            *(float4*)&out[idx] = o;
        }
    }
}

// ------- kernel 5: flash attention, 32 q/wave, KVBLK=64, VALU-diet softmax -------
// Proven R12 structure (4-wave blocks, gll16 double-buffer, counted vmcnt(8)).
// Baseline-in-accumulator + defer-max + l-sum via MFMA-with-ones.
__global__ __launch_bounds__(256, 2) void k_attn(const unsigned short* __restrict__ Q,
                                                 const unsigned short* __restrict__ K,
                                                 const unsigned short* __restrict__ V,
                                                 unsigned short* __restrict__ o_t) {
    int id = blockIdx.y * 8 + blockIdx.x;
    int bh = (id & 7) + ((id >> 6) << 3);   // XCD swizzle: all 8 q-blocks of a bh
    int qb = (id >> 3) & 7;                 // land on one XCD for K/V L2 reuse
    int t = threadIdx.x, wid = t >> 6, lane = t & 63;
    int lm = lane & 15, q4 = lane >> 4;
    __shared__ unsigned short ldsK[2][8192];  // [m=64][d=128], chunk^(m&7) swizzle
    __shared__ unsigned short ldsV[2][8192];  // [d=128][k=64], chunk^(d&7) swizzle
    const unsigned short* Qg = Q + ((size_t)bh * 1024 + qb * 128 + wid * 32) * 128;
    const unsigned short* Kg = K + (size_t)bh * 1024 * 128;
    const unsigned short* Vg = V + (size_t)bh * 128 * 1024;

    s16x8 qf0[4], qf1[4];
#pragma unroll
    for (int dc = 0; dc < 4; ++dc) {
        qf0[dc] = *(const s16x8*)&Qg[lm * 128 + dc * 32 + q4 * 8];
        qf1[dc] = *(const s16x8*)&Qg[(16 + lm) * 128 + dc * 32 + q4 * 8];
    }

    const unsigned short* gk[4];
    const unsigned short* gv[4];
    unsigned short* lkd[2][4];
    unsigned short* lvd[2][4];
#pragma unroll
    for (int h = 0; h < 4; ++h) {
        int cib = h * 256 + wid * 64;
        int ci = cib + lane;
        int mr = ci >> 4, cl = ci & 15;
        gk[h] = Kg + mr * 128 + (cl ^ (mr & 7)) * 8;
        int d = ci >> 3, kc = ci & 7;
        gv[h] = Vg + (size_t)d * 1024 + (kc ^ (d & 7)) * 8;
        lkd[0][h] = &ldsK[0][cib * 8];
        lkd[1][h] = &ldsK[1][cib * 8];
        lvd[0][h] = &ldsV[0][cib * 8];
        lvd[1][h] = &ldsV[1][cib * 8];
    }
#pragma unroll
    for (int h = 0; h < 4; ++h) { gll16(gk[h], lkd[0][h]); gll16(gv[h], lvd[0][h]); }
#pragma unroll
    for (int h = 0; h < 4; ++h) { gk[h] += 8192; gv[h] += 64; }

    f32x4 z = {0.f, 0.f, 0.f, 0.f};
    f32x4 oa[8], ob[8];
#pragma unroll
    for (int i = 0; i < 8; ++i) { oa[i] = z; ob[i] = z; }
    f32x4 lca = z, lcb = z;       // l-sums via MFMA-ones
    float mra = 0.f, mrb = 0.f;   // exp2-domain baselines
    union { s16x8 v; unsigned u[4]; } ones;
    ones.u[0] = ones.u[1] = ones.u[2] = ones.u[3] = 0x3F803F80u;  // bf16 1.0 x8

    for (int ms = 0; ms < 16; ++ms) {
        int cur = ms & 1;
        if (ms < 15) {
            int nb = cur ^ 1;
#pragma unroll
            for (int h = 0; h < 4; ++h) { gll16(gk[h], lkd[nb][h]); gll16(gv[h], lvd[nb][h]); }
#pragma unroll
            for (int h = 0; h < 4; ++h) { gk[h] += 8192; gv[h] += 64; }
            asm volatile("s_waitcnt vmcnt(8)" ::: "memory");
        } else {
            asm volatile("s_waitcnt vmcnt(0)" ::: "memory");
        }
        __builtin_amdgcn_s_barrier();
        const unsigned short* lK = ldsK[cur];
        const unsigned short* lV = ldsV[cur];

#pragma unroll
        for (int hk = 0; hk < 2; ++hk) {
            float nia = -mra, nib = -mrb;
            f32x4 sa = {nia, nia, nia, nia}, sb = {nib, nib, nib, nib};
            f32x4 sc = sa, sd = sb;
            __builtin_amdgcn_s_setprio(1);
#pragma unroll
            for (int dc = 0; dc < 4; ++dc) {
                int sw = ((dc * 4 + q4) ^ (lm & 7)) * 8;
                s16x8 k0 = *(const s16x8*)&lK[(hk * 32 + lm) * 128 + sw];
                s16x8 k1 = *(const s16x8*)&lK[(hk * 32 + 16 + lm) * 128 + sw];
                sa = MFMA16(k0, qf0[dc], sa);
                sb = MFMA16(k0, qf1[dc], sb);
                sc = MFMA16(k1, qf0[dc], sc);
                sd = MFMA16(k1, qf1[dc], sd);
            }
            __builtin_amdgcn_s_setprio(0);

            float tma = fmaxf(fmaxf(fmaxf(sa[0], sa[1]), fmaxf(sa[2], sa[3])),
                              fmaxf(fmaxf(sc[0], sc[1]), fmaxf(sc[2], sc[3])));
            float tmb = fmaxf(fmaxf(fmaxf(sb[0], sb[1]), fmaxf(sb[2], sb[3])),
                              fmaxf(fmaxf(sd[0], sd[1]), fmaxf(sd[2], sd[3])));
            if (!__all(tma <= 8.f && tmb <= 8.f)) {  // defer-max: rescale rarely
                tma = fmaxf(tma, __shfl_xor(tma, 16));
                tma = fmaxf(tma, __shfl_xor(tma, 32));
                tmb = fmaxf(tmb, __shfl_xor(tmb, 16));
                tmb = fmaxf(tmb, __shfl_xor(tmb, 32));
                float da_ = fmaxf(tma, 0.f), db_ = fmaxf(tmb, 0.f);
                float ca = exp2f_fast(-da_), cb = exp2f_fast(-db_);
                mra += da_; mrb += db_;
#pragma unroll
                for (int i = 0; i < 4; ++i) {
                    sa[i] -= da_; sc[i] -= da_;
                    sb[i] -= db_; sd[i] -= db_;
                    lca[i] *= ca; lcb[i] *= cb;
                }
#pragma unroll
                for (int t8 = 0; t8 < 8; ++t8)
#pragma unroll
                    for (int i = 0; i < 4; ++i) { oa[t8][i] *= ca; ob[t8][i] *= cb; }
            }
            float pa[8], pb[8];
#pragma unroll
            for (int i = 0; i < 4; ++i) {
                pa[i]     = exp2f_fast(sa[i]);
                pa[4 + i] = exp2f_fast(sc[i]);
                pb[i]     = exp2f_fast(sb[i]);
                pb[4 + i] = exp2f_fast(sd[i]);
            }
            union { s16x8 v; unsigned u[4]; } fa, fb;
            fa.u[0] = cvtpk(pa[0], pa[1]); fa.u[1] = cvtpk(pa[2], pa[3]);
            fa.u[2] = cvtpk(pa[4], pa[5]); fa.u[3] = cvtpk(pa[6], pa[7]);
            fb.u[0] = cvtpk(pb[0], pb[1]); fb.u[1] = cvtpk(pb[2], pb[3]);
            fb.u[2] = cvtpk(pb[4], pb[5]); fb.u[3] = cvtpk(pb[6], pb[7]);
            lca = MFMA16(ones.v, fa.v, lca);   // l += sum_k P[k][q]
            lcb = MFMA16(ones.v, fb.v, lcb);

            __builtin_amdgcn_s_setprio(1);
#pragma unroll
            for (int t8 = 0; t8 < 8; ++t8) {
                int r = t8 * 16 + lm;
                s16x8 vf = *(const s16x8*)&lV[r * 64 + (((hk * 4 + q4) ^ (lm & 7)) * 8)];
                oa[t8] = MFMA16(vf, fa.v, oa[t8]);
                ob[t8] = MFMA16(vf, fb.v, ob[t8]);
            }
            __builtin_amdgcn_s_setprio(0);
        }
        __builtin_amdgcn_s_barrier();
    }

    float inva = 1.f / lca[0], invb = 1.f / lcb[0];
    int b = bh >> 2, head = bh & 3;
    size_t rowa = (size_t)b * 1024 + qb * 128 + wid * 32 + lm;
    unsigned short* da = o_t + rowa * 512 + head * 128;
    unsigned short* db = da + (size_t)16 * 512;
#pragma unroll
    for (int t8 = 0; t8 < 8; ++t8) {
        uint2 pr;
        pr.x = cvtpk(oa[t8][0] * inva, oa[t8][1] * inva);
        pr.y = cvtpk(oa[t8][2] * inva, oa[t8][3] * inva);
        *(uint2*)&da[t8 * 16 + q4 * 4] = pr;
        pr.x = cvtpk(ob[t8][0] * invb, ob[t8][1] * invb);
        pr.y = cvtpk(ob[t8][2] * invb, ob[t8][3] * invb);
        *(uint2*)&db[t8 * 16 + q4 * 4] = pr;
    }
}

extern "C" void kernel_launch(void* const* d_in, const int* in_sizes, int n_in,
                              void* d_out, int out_size, void* d_ws, size_t ws_size,
                              hipStream_t stream) {
    const float* x = (const float*)d_in[0];
    const float* gnw = (const float*)d_in[1];
    const float* gnb = (const float*)d_in[2];
    const float* qkvw = (const float*)d_in[3];
    const float* qkvb = (const float*)d_in[4];
    const float* projw = (const float*)d_in[5];
    const float* projb = (const float*)d_in[6];
    float* out = (float*)d_out;
    char* ws = (char*)d_ws;

    unsigned short* wq = (unsigned short*)(ws);                  // 1536x512 bf16
    unsigned short* wp = (unsigned short*)(ws + 1572864);        // 512x512 bf16
    unsigned short* ht = (unsigned short*)(ws + 2101248);        // h_t [16384][512] bf16
    unsigned short* Qb = (unsigned short*)(ws + 18878464);       // [64][1024][128] (pre-scaled)
    unsigned short* Kb = (unsigned short*)(ws + 35655680);       // [64][1024][128]
    unsigned short* Vb = (unsigned short*)(ws + 52432896);       // [64][128][1024] (m-permuted)
    unsigned short* ot = ht;                                     // reuse h_t region

    k_gnw<<<dim3(4608), dim3(256), 0, stream>>>(x, gnw, gnb, qkvw, projw, ht, wq);
    k_gemmqkv<<<dim3(1536), dim3(512), 0, stream>>>(wq, ht, qkvb, Qb, Kb, Vb);
    k_attn<<<dim3(8, 64), dim3(256), 0, stream>>>(Qb, Kb, Vb, ot);
    k_gemmproj<<<dim3(512), dim3(512), 0, stream>>>(wp, ot, projb, x, out);
}

// Round 16
// 119.206 us; speedup vs baseline: 1.0274x; 1.0274x over previous
//
#include <hip/hip_runtime.h>

typedef __attribute__((ext_vector_type(4))) float f32x4;
typedef __attribute__((ext_vector_type(8))) short s16x8;

#define MFMA16(a, b, c) __builtin_amdgcn_mfma_f32_16x16x32_bf16((a), (b), (c), 0, 0, 0)

__device__ __forceinline__ unsigned short f2bf(float f) {
    union { float f; unsigned u; } v; v.f = f;
    unsigned u = v.u + 0x7FFFu + ((v.u >> 16) & 1u);
    return (unsigned short)(u >> 16);
}

__device__ __forceinline__ unsigned cvtpk(float lo, float hi) {
    unsigned r;
    asm("v_cvt_pk_bf16_f32 %0, %1, %2" : "=v"(r) : "v"(lo), "v"(hi));
    return r;
}

__device__ __forceinline__ float exp2f_fast(float x) {
    float r;
    asm("v_exp_f32 %0, %1" : "=v"(r) : "v"(x));
    return r;
}

__device__ __forceinline__ void gll16(const unsigned short* g, unsigned short* l) {
    __builtin_amdgcn_global_load_lds((const __attribute__((address_space(1))) void*)g,
                                     (__attribute__((address_space(3))) void*)l, 16, 0, 0);
}

// ---- kernel 1+2 fused: weight convert (blocks >= 512, float4) / group-norm ----
__global__ __launch_bounds__(256) void k_gnw(const float* __restrict__ x,
                                             const float* __restrict__ gnw,
                                             const float* __restrict__ gnb,
                                             const float* __restrict__ qkv_w,
                                             const float* __restrict__ proj_w,
                                             unsigned short* __restrict__ h_t,
                                             unsigned short* __restrict__ wout) {
    __shared__ float rs[4], rss[4], mv[2];
    __shared__ unsigned short ldt[1024][18];  // padded: stride 36B kills conflicts
    int blk = blockIdx.x;
    int t = threadIdx.x;
    if (blk >= 512) {
        // weight convert: 4 floats/thread. 1M elems / (256*4) = 1024 blocks.
        int i = ((blk - 512) * 256 + t) * 4;
        const int NQ = 3 * 512 * 512;
        float4 v = (i < NQ) ? *(const float4*)(qkv_w + i)
                            : *(const float4*)(proj_w + (i - NQ));
        uint2 pr;
        pr.x = cvtpk(v.x, v.y);
        pr.y = cvtpk(v.z, v.w);
        *(uint2*)(wout + i) = pr;
        return;
    }
    int bg = blk;
    int b = bg >> 5, g = bg & 31;
    const float4* p = (const float4*)(x + (size_t)bg * 16384);
    float s = 0.f, ss = 0.f;
    for (int i = t; i < 4096; i += 256) {
        float4 v = p[i];
        s += v.x + v.y + v.z + v.w;
        ss += v.x * v.x + v.y * v.y + v.z * v.z + v.w * v.w;
    }
    for (int w = 1; w < 64; w <<= 1) { s += __shfl_xor(s, w); ss += __shfl_xor(ss, w); }
    int wid = t >> 6;
    if ((t & 63) == 0) { rs[wid] = s; rss[wid] = ss; }
    __syncthreads();
    if (t == 0) {
        float S = rs[0] + rs[1] + rs[2] + rs[3];
        float SS = rss[0] + rss[1] + rss[2] + rss[3];
        float mean = S * (1.f / 16384.f);
        float var = SS * (1.f / 16384.f) - mean * mean;
        mv[0] = mean; mv[1] = rsqrtf(var + 1e-5f);
    }
    __syncthreads();
    int c = t >> 4, f4 = t & 15;
    float mean = mv[0], rstd = mv[1];
    float sc = gnw[g * 16 + c] * rstd;
    float sh = gnb[g * 16 + c] - mean * sc;
    const float4* pc = (const float4*)(x + ((size_t)(b * 512 + g * 16 + c)) * 1024);
#pragma unroll
    for (int i = 0; i < 16; ++i) {
        int n = i * 64 + f4 * 4;
        float4 v = pc[n >> 2];
        ldt[n + 0][c] = f2bf(v.x * sc + sh);
        ldt[n + 1][c] = f2bf(v.y * sc + sh);
        ldt[n + 2][c] = f2bf(v.z * sc + sh);
        ldt[n + 3][c] = f2bf(v.w * sc + sh);
    }
    __syncthreads();
    int half = t & 1;
#pragma unroll
    for (int i = 0; i < 8; ++i) {
        int row = i * 128 + (t >> 1);
        *(uint4*)(h_t + ((size_t)(b * 1024 + row)) * 512 + g * 16 + half * 8) =
            *(const uint4*)(&ldt[row][half * 8]);
    }
}

// ---- merged QKV BT-GEMM, 128x128 tile, 8 waves (wave-tile 64x32), K=512 ----
// mt 0..7: Q/K tiles, unswapped MFMA, uint2 bf16 stores
// mt 8..11: V tiles, swapped MFMA (D rows = pixels), permuted-m uint2 stores
// Block-uniform branch, two separate loop bodies (no per-iteration branching).
__global__ __launch_bounds__(512, 6) void k_gemmqkv(const unsigned short* __restrict__ A,
                                                    const unsigned short* __restrict__ Bt,
                                                    const float* __restrict__ bias,
                                                    unsigned short* __restrict__ Qo,
                                                    unsigned short* __restrict__ Ko,
                                                    unsigned short* __restrict__ Vo) {
    const int Kd = 512;
    int id = blockIdx.x;
    int xcd = id & 7, j = id >> 3;
    int nt = xcd + 8 * (j & 15);   // B-tile: 16 per XCD, L2-resident
    int mt = j >> 4;               // 0..11
    int t = threadIdx.x, wid = t >> 6, lane = t & 63;
    int lm = lane & 15, q4 = lane >> 4;
    int wm = wid >> 2, wn = wid & 3;  // 2 (m) x 4 (n) waves; wave-tile 64x32
    __shared__ unsigned short ldsA[2][4096];
    __shared__ unsigned short ldsB[2][4096];
    int m0 = mt * 128, n0 = nt * 128;

    int r = t >> 2;
    int cc = (t & 3) ^ (r & 3);  // chunk-XOR swizzle folded into global src
    const unsigned short* gA = A + (size_t)(m0 + r) * Kd + cc * 8;
    const unsigned short* gB = Bt + (size_t)(n0 + r) * Kd + cc * 8;
    unsigned short* dA[2] = { &ldsA[0][wid * 512], &ldsA[1][wid * 512] };
    unsigned short* dB[2] = { &ldsB[0][wid * 512], &ldsB[1][wid * 512] };

    f32x4 z = {0.f, 0.f, 0.f, 0.f};
    f32x4 acc[4][2];
#pragma unroll
    for (int fi = 0; fi < 4; ++fi)
#pragma unroll
        for (int fj = 0; fj < 2; ++fj) acc[fi][fj] = z;

    gll16(gA, dA[0]); gll16(gB, dB[0]);
    gA += 32; gB += 32;

    const int NK = 16;
    int b = nt >> 3;
    if (mt < 8) {
        // ---------------- unswapped loop (Q/K) ----------------
        for (int ks = 0; ks < NK; ++ks) {
            int cur = ks & 1;
            if (ks + 1 < NK) {
                gll16(gA, dA[cur ^ 1]); gll16(gB, dB[cur ^ 1]);
                gA += 32; gB += 32;
                asm volatile("s_waitcnt vmcnt(2)" ::: "memory");
            } else {
                asm volatile("s_waitcnt vmcnt(0)" ::: "memory");
            }
            __builtin_amdgcn_s_barrier();
            asm volatile("" ::: "memory");
            const unsigned short* lA = ldsA[cur];
            const unsigned short* lB = ldsB[cur];
            s16x8 af[4], bg[2];
#pragma unroll
            for (int fi = 0; fi < 4; ++fi) {
                int rA = wm * 64 + fi * 16 + lm;
                af[fi] = *(const s16x8*)&lA[(rA * 4 + (q4 ^ (lm & 3))) * 8];
            }
#pragma unroll
            for (int fj = 0; fj < 2; ++fj) {
                int rB = wn * 32 + fj * 16 + lm;
                bg[fj] = *(const s16x8*)&lB[(rB * 4 + (q4 ^ (lm & 3))) * 8];
            }
#pragma unroll
            for (int fi = 0; fi < 4; ++fi)
#pragma unroll
                for (int fj = 0; fj < 2; ++fj) acc[fi][fj] = MFMA16(af[fi], bg[fj], acc[fi][fj]);
            asm volatile("" ::: "memory");
            __builtin_amdgcn_s_barrier();
        }
        int part = mt >> 2;  // 0=Q (mt 0..3), 1=K (mt 4..7)
        int head = mt & 3;
        int bh = b * 4 + head;
        const float qscale = 0.08838834764831845f * 1.4426950408889634f;  // 1/sqrt(128)*log2e
#pragma unroll
        for (int fi = 0; fi < 4; ++fi) {
            int ddb = wm * 64 + fi * 16 + 4 * q4;
            float bv[4];
#pragma unroll
            for (int i = 0; i < 4; ++i) bv[i] = bias[mt * 128 + ddb + i];
#pragma unroll
            for (int fj = 0; fj < 2; ++fj) {
                int n = ((nt & 7) << 7) + wn * 32 + fj * 16 + lm;
                f32x4 v = acc[fi][fj];
                uint2 pr;
                if (part == 0) {
                    pr.x = cvtpk((v[0] + bv[0]) * qscale, (v[1] + bv[1]) * qscale);
                    pr.y = cvtpk((v[2] + bv[2]) * qscale, (v[3] + bv[3]) * qscale);
                    *(uint2*)(Qo + ((size_t)bh * 1024 + n) * 128 + ddb) = pr;
                } else {
                    pr.x = cvtpk(v[0] + bv[0], v[1] + bv[1]);
                    pr.y = cvtpk(v[2] + bv[2], v[3] + bv[3]);
                    *(uint2*)(Ko + ((size_t)bh * 1024 + n) * 128 + ddb) = pr;
                }
            }
        }
    } else {
        // ---------------- swapped loop (V) ----------------
        for (int ks = 0; ks < NK; ++ks) {
            int cur = ks & 1;
            if (ks + 1 < NK) {
                gll16(gA, dA[cur ^ 1]); gll16(gB, dB[cur ^ 1]);
                gA += 32; gB += 32;
                asm volatile("s_waitcnt vmcnt(2)" ::: "memory");
            } else {
                asm volatile("s_waitcnt vmcnt(0)" ::: "memory");
            }
            __builtin_amdgcn_s_barrier();
            asm volatile("" ::: "memory");
            const unsigned short* lA = ldsA[cur];
            const unsigned short* lB = ldsB[cur];
            s16x8 af[4], bg[2];
#pragma unroll
            for (int fi = 0; fi < 4; ++fi) {
                int rA = wm * 64 + fi * 16 + lm;
                af[fi] = *(const s16x8*)&lA[(rA * 4 + (q4 ^ (lm & 3))) * 8];
            }
#pragma unroll
            for (int fj = 0; fj < 2; ++fj) {
                int rB = wn * 32 + fj * 16 + lm;
                bg[fj] = *(const s16x8*)&lB[(rB * 4 + (q4 ^ (lm & 3))) * 8];
            }
#pragma unroll
            for (int fi = 0; fi < 4; ++fi)
#pragma unroll
                for (int fj = 0; fj < 2; ++fj) acc[fi][fj] = MFMA16(bg[fj], af[fi], acc[fi][fj]);
            asm volatile("" ::: "memory");
            __builtin_amdgcn_s_barrier();
        }
        // lane col lm = d, rows = pixel (4 consecutive) -> permuted uint2
        int bh = b * 4 + (mt & 3);
#pragma unroll
        for (int fi = 0; fi < 4; ++fi) {
            int d = wm * 64 + fi * 16 + lm;
            float bv = bias[mt * 128 + d];
#pragma unroll
            for (int fj = 0; fj < 2; ++fj) {
                int np = ((nt & 7) << 7) + wn * 32 + q4 * 8 + fj * 4;
                f32x4 v = acc[fi][fj];
                uint2 pr;
                pr.x = cvtpk(v[0] + bv, v[1] + bv);
                pr.y = cvtpk(v[2] + bv, v[3] + bv);
                *(uint2*)(Vo + ((size_t)bh * 128 + d) * 1024 + np) = pr;
            }
        }
    }
}

// ---------------- proj BT-GEMM (swapped), float4 xres/out epilogue ----------------
__global__ __launch_bounds__(512, 6) void k_gemmproj(const unsigned short* __restrict__ A,
                                                     const unsigned short* __restrict__ Bt,
                                                     const float* __restrict__ bias,
                                                     const float* __restrict__ xres,
                                                     float* __restrict__ out) {
    const int Kd = 512;
    int id = blockIdx.x;
    int xcd = id & 7, j = id >> 3;
    int nt = xcd + 8 * (j & 15);
    int mt = j >> 4;
    int t = threadIdx.x, wid = t >> 6, lane = t & 63;
    int lm = lane & 15, q4 = lane >> 4;
    int wm = wid >> 2, wn = wid & 3;
    __shared__ unsigned short ldsA[2][4096];
    __shared__ unsigned short ldsB[2][4096];
    int m0 = mt * 128, n0 = nt * 128;

    int r = t >> 2;
    int cc = (t & 3) ^ (r & 3);
    const unsigned short* gA = A + (size_t)(m0 + r) * Kd + cc * 8;
    const unsigned short* gB = Bt + (size_t)(n0 + r) * Kd + cc * 8;
    unsigned short* dA[2] = { &ldsA[0][wid * 512], &ldsA[1][wid * 512] };
    unsigned short* dB[2] = { &ldsB[0][wid * 512], &ldsB[1][wid * 512] };

    f32x4 z = {0.f, 0.f, 0.f, 0.f};
    f32x4 acc[4][2];
#pragma unroll
    for (int fi = 0; fi < 4; ++fi)
#pragma unroll
        for (int fj = 0; fj < 2; ++fj) acc[fi][fj] = z;

    gll16(gA, dA[0]); gll16(gB, dB[0]);
    gA += 32; gB += 32;

    const int NK = 16;
    for (int ks = 0; ks < NK; ++ks) {
        int cur = ks & 1;
        if (ks + 1 < NK) {
            gll16(gA, dA[cur ^ 1]); gll16(gB, dB[cur ^ 1]);
            gA += 32; gB += 32;
            asm volatile("s_waitcnt vmcnt(2)" ::: "memory");
        } else {
            asm volatile("s_waitcnt vmcnt(0)" ::: "memory");
        }
        __builtin_amdgcn_s_barrier();
        asm volatile("" ::: "memory");
        const unsigned short* lA = ldsA[cur];
        const unsigned short* lB = ldsB[cur];
        s16x8 af[4], bg[2];
#pragma unroll
        for (int fi = 0; fi < 4; ++fi) {
            int rA = wm * 64 + fi * 16 + lm;
            af[fi] = *(const s16x8*)&lA[(rA * 4 + (q4 ^ (lm & 3))) * 8];
        }
#pragma unroll
        for (int fj = 0; fj < 2; ++fj) {
            int rB = wn * 32 + fj * 16 + lm;
            bg[fj] = *(const s16x8*)&lB[(rB * 4 + (q4 ^ (lm & 3))) * 8];
        }
#pragma unroll
        for (int fi = 0; fi < 4; ++fi)
#pragma unroll
            for (int fj = 0; fj < 2; ++fj) acc[fi][fj] = MFMA16(bg[fj], af[fi], acc[fi][fj]);
        asm volatile("" ::: "memory");
        __builtin_amdgcn_s_barrier();
    }

    int b = nt >> 3;
#pragma unroll
    for (int fi = 0; fi < 4; ++fi) {
        int oc = m0 + wm * 64 + fi * 16 + lm;
        float bv = bias[oc];
#pragma unroll
        for (int fj = 0; fj < 2; ++fj) {
            int n = ((nt & 7) << 7) + wn * 32 + fj * 16 + 4 * q4;
            size_t idx = ((size_t)b * 512 + oc) * 1024 + n;
            float4 xr = *(const float4*)&xres[idx];
            f32x4 v = acc[fi][fj];
            float4 o;
            o.x = xr.x + bv + v[0];
            o.y = xr.y + bv + v[1];
            o.z = xr.z + bv + v[2];
            o.w = xr.w + bv + v[3];
            *(float4*)&out[idx] = o;
        }
    }
}

// ------- kernel 5: flash attention, 32 q/wave, KVBLK=64, VALU-diet softmax -------
// Proven R12 structure (4-wave blocks, gll16 double-buffer, counted vmcnt(8)).
// Baseline-in-accumulator + defer-max + l-sum via MFMA-with-ones.
__global__ __launch_bounds__(256, 2) void k_attn(const unsigned short* __restrict__ Q,
                                                 const unsigned short* __restrict__ K,
                                                 const unsigned short* __restrict__ V,
                                                 unsigned short* __restrict__ o_t) {
    int id = blockIdx.y * 8 + blockIdx.x;
    int bh = (id & 7) + ((id >> 6) << 3);   // XCD swizzle: all 8 q-blocks of a bh
    int qb = (id >> 3) & 7;                 // land on one XCD for K/V L2 reuse
    int t = threadIdx.x, wid = t >> 6, lane = t & 63;
    int lm = lane & 15, q4 = lane >> 4;
    __shared__ unsigned short ldsK[2][8192];  // [m=64][d=128], chunk^(m&7) swizzle
    __shared__ unsigned short ldsV[2][8192];  // [d=128][k=64], chunk^(d&7) swizzle
    const unsigned short* Qg = Q + ((size_t)bh * 1024 + qb * 128 + wid * 32) * 128;
    const unsigned short* Kg = K + (size_t)bh * 1024 * 128;
    const unsigned short* Vg = V + (size_t)bh * 128 * 1024;

    s16x8 qf0[4], qf1[4];
#pragma unroll
    for (int dc = 0; dc < 4; ++dc) {
        qf0[dc] = *(const s16x8*)&Qg[lm * 128 + dc * 32 + q4 * 8];
        qf1[dc] = *(const s16x8*)&Qg[(16 + lm) * 128 + dc * 32 + q4 * 8];
    }

    const unsigned short* gk[4];
    const unsigned short* gv[4];
    unsigned short* lkd[2][4];
    unsigned short* lvd[2][4];
#pragma unroll
    for (int h = 0; h < 4; ++h) {
        int cib = h * 256 + wid * 64;
        int ci = cib + lane;
        int mr = ci >> 4, cl = ci & 15;
        gk[h] = Kg + mr * 128 + (cl ^ (mr & 7)) * 8;
        int d = ci >> 3, kc = ci & 7;
        gv[h] = Vg + (size_t)d * 1024 + (kc ^ (d & 7)) * 8;
        lkd[0][h] = &ldsK[0][cib * 8];
        lkd[1][h] = &ldsK[1][cib * 8];
        lvd[0][h] = &ldsV[0][cib * 8];
        lvd[1][h] = &ldsV[1][cib * 8];
    }
#pragma unroll
    for (int h = 0; h < 4; ++h) { gll16(gk[h], lkd[0][h]); gll16(gv[h], lvd[0][h]); }
#pragma unroll
    for (int h = 0; h < 4; ++h) { gk[h] += 8192; gv[h] += 64; }

    f32x4 z = {0.f, 0.f, 0.f, 0.f};
    f32x4 oa[8], ob[8];
#pragma unroll
    for (int i = 0; i < 8; ++i) { oa[i] = z; ob[i] = z; }
    f32x4 lca = z, lcb = z;       // l-sums via MFMA-ones
    float mra = 0.f, mrb = 0.f;   // exp2-domain baselines
    union { s16x8 v; unsigned u[4]; } ones;
    ones.u[0] = ones.u[1] = ones.u[2] = ones.u[3] = 0x3F803F80u;  // bf16 1.0 x8

    for (int ms = 0; ms < 16; ++ms) {
        int cur = ms & 1;
        if (ms < 15) {
            int nb = cur ^ 1;
#pragma unroll
            for (int h = 0; h < 4; ++h) { gll16(gk[h], lkd[nb][h]); gll16(gv[h], lvd[nb][h]); }
#pragma unroll
            for (int h = 0; h < 4; ++h) { gk[h] += 8192; gv[h] += 64; }
            asm volatile("s_waitcnt vmcnt(8)" ::: "memory");
        } else {
            asm volatile("s_waitcnt vmcnt(0)" ::: "memory");
        }
        __builtin_amdgcn_s_barrier();
        const unsigned short* lK = ldsK[cur];
        const unsigned short* lV = ldsV[cur];

#pragma unroll
        for (int hk = 0; hk < 2; ++hk) {
            float nia = -mra, nib = -mrb;
            f32x4 sa = {nia, nia, nia, nia}, sb = {nib, nib, nib, nib};
            f32x4 sc = sa, sd = sb;
            __builtin_amdgcn_s_setprio(1);
#pragma unroll
            for (int dc = 0; dc < 4; ++dc) {
                int sw = ((dc * 4 + q4) ^ (lm & 7)) * 8;
                s16x8 k0 = *(const s16x8*)&lK[(hk * 32 + lm) * 128 + sw];
                s16x8 k1 = *(const s16x8*)&lK[(hk * 32 + 16 + lm) * 128 + sw];
                sa = MFMA16(k0, qf0[dc], sa);
                sb = MFMA16(k0, qf1[dc], sb);
                sc = MFMA16(k1, qf0[dc], sc);
                sd = MFMA16(k1, qf1[dc], sd);
            }
            __builtin_amdgcn_s_setprio(0);

            float tma = fmaxf(fmaxf(fmaxf(sa[0], sa[1]), fmaxf(sa[2], sa[3])),
                              fmaxf(fmaxf(sc[0], sc[1]), fmaxf(sc[2], sc[3])));
            float tmb = fmaxf(fmaxf(fmaxf(sb[0], sb[1]), fmaxf(sb[2], sb[3])),
                              fmaxf(fmaxf(sd[0], sd[1]), fmaxf(sd[2], sd[3])));
            if (!__all(tma <= 8.f && tmb <= 8.f)) {  // defer-max: rescale rarely
                tma = fmaxf(tma, __shfl_xor(tma, 16));
                tma = fmaxf(tma, __shfl_xor(tma, 32));
                tmb = fmaxf(tmb, __shfl_xor(tmb, 16));
                tmb = fmaxf(tmb, __shfl_xor(tmb, 32));
                float da_ = fmaxf(tma, 0.f), db_ = fmaxf(tmb, 0.f);
                float ca = exp2f_fast(-da_), cb = exp2f_fast(-db_);
                mra += da_; mrb += db_;
#pragma unroll
                for (int i = 0; i < 4; ++i) {
                    sa[i] -= da_; sc[i] -= da_;
                    sb[i] -= db_; sd[i] -= db_;
                    lca[i] *= ca; lcb[i] *= cb;
                }
#pragma unroll
                for (int t8 = 0; t8 < 8; ++t8)
#pragma unroll
                    for (int i = 0; i < 4; ++i) { oa[t8][i] *= ca; ob[t8][i] *= cb; }
            }
            float pa[8], pb[8];
#pragma unroll
            for (int i = 0; i < 4; ++i) {
                pa[i]     = exp2f_fast(sa[i]);
                pa[4 + i] = exp2f_fast(sc[i]);
                pb[i]     = exp2f_fast(sb[i]);
                pb[4 + i] = exp2f_fast(sd[i]);
            }
            union { s16x8 v; unsigned u[4]; } fa, fb;
            fa.u[0] = cvtpk(pa[0], pa[1]); fa.u[1] = cvtpk(pa[2], pa[3]);
            fa.u[2] = cvtpk(pa[4], pa[5]); fa.u[3] = cvtpk(pa[6], pa[7]);
            fb.u[0] = cvtpk(pb[0], pb[1]); fb.u[1] = cvtpk(pb[2], pb[3]);
            fb.u[2] = cvtpk(pb[4], pb[5]); fb.u[3] = cvtpk(pb[6], pb[7]);
            lca = MFMA16(ones.v, fa.v, lca);   // l += sum_k P[k][q]
            lcb = MFMA16(ones.v, fb.v, lcb);

            __builtin_amdgcn_s_setprio(1);
#pragma unroll
            for (int t8 = 0; t8 < 8; ++t8) {
                int r = t8 * 16 + lm;
                s16x8 vf = *(const s16x8*)&lV[r * 64 + (((hk * 4 + q4) ^ (lm & 7)) * 8)];
                oa[t8] = MFMA16(vf, fa.v, oa[t8]);
                ob[t8] = MFMA16(vf, fb.v, ob[t8]);
            }
            __builtin_amdgcn_s_setprio(0);
        }
        __builtin_amdgcn_s_barrier();
    }

    float inva = 1.f / lca[0], invb = 1.f / lcb[0];
    int b = bh >> 2, head = bh & 3;
    size_t rowa = (size_t)b * 1024 + qb * 128 + wid * 32 + lm;
    unsigned short* da = o_t + rowa * 512 + head * 128;
    unsigned short* db = da + (size_t)16 * 512;
#pragma unroll
    for (int t8 = 0; t8 < 8; ++t8) {
        uint2 pr;
        pr.x = cvtpk(oa[t8][0] * inva, oa[t8][1] * inva);
        pr.y = cvtpk(oa[t8][2] * inva, oa[t8][3] * inva);
        *(uint2*)&da[t8 * 16 + q4 * 4] = pr;
        pr.x = cvtpk(ob[t8][0] * invb, ob[t8][1] * invb);
        pr.y = cvtpk(ob[t8][2] * invb, ob[t8][3] * invb);
        *(uint2*)&db[t8 * 16 + q4 * 4] = pr;
    }
}

extern "C" void kernel_launch(void* const* d_in, const int* in_sizes, int n_in,
                              void* d_out, int out_size, void* d_ws, size_t ws_size,
                              hipStream_t stream) {
    const float* x = (const float*)d_in[0];
    const float* gnw = (const float*)d_in[1];
    const float* gnb = (const float*)d_in[2];
    const float* qkvw = (const float*)d_in[3];
    const float* qkvb = (const float*)d_in[4];
    const float* projw = (const float*)d_in[5];
    const float* projb = (const float*)d_in[6];
    float* out = (float*)d_out;
    char* ws = (char*)d_ws;

    unsigned short* wq = (unsigned short*)(ws);                  // 1536x512 bf16
    unsigned short* wp = (unsigned short*)(ws + 1572864);        // 512x512 bf16
    unsigned short* ht = (unsigned short*)(ws + 2101248);        // h_t [16384][512] bf16
    unsigned short* Qb = (unsigned short*)(ws + 18878464);       // [64][1024][128] (pre-scaled)
    unsigned short* Kb = (unsigned short*)(ws + 35655680);       // [64][1024][128]
    unsigned short* Vb = (unsigned short*)(ws + 52432896);       // [64][128][1024] (m-permuted)
    unsigned short* ot = ht;                                     // reuse h_t region

    k_gnw<<<dim3(1536), dim3(256), 0, stream>>>(x, gnw, gnb, qkvw, projw, ht, wq);
    k_gemmqkv<<<dim3(1536), dim3(512), 0, stream>>>(wq, ht, qkvb, Qb, Kb, Vb);
    k_attn<<<dim3(8, 64), dim3(256), 0, stream>>>(Qb, Kb, Vb, ot);
    k_gemmproj<<<dim3(512), dim3(512), 0, stream>>>(wp, ot, projb, x, out);
}